// Round 1
// 975.922 us; speedup vs baseline: 1.4947x; 1.4947x over previous
//
#include <hip/hip_runtime.h>
#include <hip/hip_bf16.h>
#include <cstdio>

typedef __bf16 bf16;
typedef __bf16 bf16x4 __attribute__((ext_vector_type(4)));
typedef __bf16 bf16x8 __attribute__((ext_vector_type(8)));
typedef float  f32x4  __attribute__((ext_vector_type(4)));

#define AS1 __attribute__((address_space(1)))
#define AS3 __attribute__((address_space(3)))

__device__ __forceinline__ void async16(void* lds, const void* g) {
    __builtin_amdgcn_global_load_lds((AS1 unsigned int*)g, (AS3 unsigned int*)lds, 16, 0, 0);
}

enum { EPI_NONE = 0, EPI_SINUS = 1, EPI_BIAS = 2 };

constexpr int BM = 128, BN = 128, BK = 32;

// C[m][n] = sum_k A[m][k] * B[n][k]   (NT gemm, both operands K-contiguous, bf16 in, CT out)
// grid: (N/BN, M/BM, batch)
template <int EPI, typename CT>
__launch_bounds__(256)
__global__ void gemm_nt(const bf16* __restrict__ A, long sA, int lda,
                        const bf16* __restrict__ B, long sB, int ldb,
                        CT* __restrict__ C, long sC, int ldc,
                        int K, int mLimit,
                        const float* __restrict__ bias)
{
    __shared__ __align__(16) bf16 As[BM * BK];
    __shared__ __align__(16) bf16 Bs[BN * BK];

    const int tid  = threadIdx.x;
    const int wave = tid >> 6;
    const int lane = tid & 63;
    const int quad = lane >> 4;
    const int l16  = lane & 15;
    const int b    = blockIdx.z;
    const int m0   = blockIdx.y * BM;
    const int n0   = blockIdx.x * BN;

    A += (long)b * sA;
    B += (long)b * sB;

    // staging: wave w covers rows [w*32, w*32+32); lane L -> row L/4, kpart (L%4)*8 elems
    const int srow = lane >> 2;
    const int scol = (lane & 3) * 8;
    const bf16* gA = A + (long)(m0 + wave * 32 + srow) * lda + scol;
    const bf16* gB = B + (long)(n0 + wave * 32 + srow) * ldb + scol;
    char* lA = (char*)As + wave * 2048;   // 32 rows * 64B
    char* lB = (char*)Bs + wave * 2048;

    const int wm = (wave >> 1) * 64;
    const int wn = (wave & 1) * 64;

    f32x4 acc[4][4] = {};

    for (int k0 = 0; k0 < K; k0 += BK) {
        __syncthreads();                       // prev-iter LDS reads done
        async16(lA,        gA);
        async16(lA + 1024, gA + (long)16 * lda);
        async16(lB,        gB);
        async16(lB + 1024, gB + (long)16 * ldb);
        gA += BK; gB += BK;
        __syncthreads();                       // drains vmcnt: tiles resident

        bf16x8 af[4], bfr[4];
        #pragma unroll
        for (int i = 0; i < 4; i++) {
            af[i]  = *(const bf16x8*)(As + (wm + i * 16 + l16) * BK + quad * 8);
            bfr[i] = *(const bf16x8*)(Bs + (wn + i * 16 + l16) * BK + quad * 8);
        }
        #pragma unroll
        for (int mi = 0; mi < 4; mi++)
            #pragma unroll
            for (int ni = 0; ni < 4; ni++)
                acc[mi][ni] = __builtin_amdgcn_mfma_f32_16x16x32_bf16(
                    af[mi], bfr[ni], acc[mi][ni], 0, 0, 0);
    }

    C += (long)b * sC;

    #pragma unroll
    for (int ni = 0; ni < 4; ni++) {
        const int col = n0 + wn + ni * 16 + l16;
        float fr = 0.f;
        if (EPI == EPI_SINUS)
            fr = __expf((float)(-(col & ~1)) * (9.210340371976184f / 1024.f)); // exp(-(2i)ln(1e4)/d)
        #pragma unroll
        for (int mi = 0; mi < 4; mi++) {
            #pragma unroll
            for (int r = 0; r < 4; r++) {
                const int row = m0 + wm + mi * 16 + quad * 4 + r; // C/D: row=quad*4+reg, col=lane&15
                float v = acc[mi][ni][r];
                if (EPI == EPI_SINUS) {
                    float ang = (float)row * fr;
                    // __sinf/__cosf: inline v_sin_f32/v_cos_f32, no libcall (libcall ABI
                    // clamped the kernel to 44 VGPRs and spilled the acc tile -> 3.7 GB scratch)
                    v += (col & 1) ? __cosf(ang) : __sinf(ang);
                }
                if (EPI == EPI_BIAS) v += bias[row];
                if (row < mLimit)
                    C[(long)row * ldc + col] = (CT)v;
            }
        }
    }
}

// f32 -> bf16 flat convert (n % 4 == 0)
__launch_bounds__(256)
__global__ void cvt_f32_bf16(const float* __restrict__ in, bf16* __restrict__ out, int n)
{
    int i = (blockIdx.x * 256 + threadIdx.x) * 4;
    if (i < n) {
        float4 v = *(const float4*)(in + i);
        out[i]     = (bf16)v.x;
        out[i + 1] = (bf16)v.y;
        out[i + 2] = (bf16)v.z;
        out[i + 3] = (bf16)v.w;
    }
}

// batched transpose + f32->bf16: in (rows x cols) f32 -> out (cols x rows) bf16
__launch_bounds__(256)
__global__ void transpose_f32_bf16(const float* __restrict__ in, bf16* __restrict__ out,
                                   int rows, int cols)
{
    __shared__ float tile[32][33];
    const long bs = (long)rows * cols;
    in  += (long)blockIdx.z * bs;
    out += (long)blockIdx.z * bs;
    const int c0 = blockIdx.x * 32, r0 = blockIdx.y * 32;
    const int tx = threadIdx.x, ty = threadIdx.y;
    #pragma unroll
    for (int i = ty; i < 32; i += 8)
        tile[i][tx] = in[(long)(r0 + i) * cols + c0 + tx];
    __syncthreads();
    #pragma unroll
    for (int i = ty; i < 32; i += 8)
        out[(long)(c0 + i) * rows + r0 + tx] = (bf16)tile[tx][i];
}

// batched bf16 transpose: in (rows x cols) -> out (cols x rows)
__launch_bounds__(256)
__global__ void transpose_bf16(const bf16* __restrict__ in, bf16* __restrict__ out,
                               int rows, int cols)
{
    __shared__ bf16 tile[32][33];
    const long bs = (long)rows * cols;
    in  += (long)blockIdx.z * bs;
    out += (long)blockIdx.z * bs;
    const int c0 = blockIdx.x * 32, r0 = blockIdx.y * 32;
    const int tx = threadIdx.x, ty = threadIdx.y;
    #pragma unroll
    for (int i = ty; i < 32; i += 8)
        tile[i][tx] = in[(long)(r0 + i) * cols + c0 + tx];
    __syncthreads();
    #pragma unroll
    for (int i = ty; i < 32; i += 8)
        out[(long)(c0 + i) * rows + r0 + tx] = tile[tx][i];
}

// ---------- column softmax over m of attn (f32, (1023,1024) per batch) ----------
// Split-m parallel version: grid (4 col-tiles, 8 m-chunks, 32 batches) per pass.
// Old single-pass version ran 128 blocks with per-thread 1023-long serial chains:
// 4.5% occupancy, 566 us, pure latency exposure. This splits m 8-ways across
// blocks + 4-ways across waves (32-iter chains) -> 1024 blocks, float4 loads.

__device__ __forceinline__ void onl_upd(float v, float& mx, float& sm) {
    if (v > mx) { sm = sm * __expf(mx - v) + 1.f; mx = v; }
    else        { sm += __expf(v - mx); }
}

__device__ __forceinline__ void onl_merge(float& mx, float& sm, float omx, float osm) {
    float nm = fmaxf(mx, omx);
    sm = sm * __expf(mx - nm) + osm * __expf(omx - nm);
    mx = nm;
}

// pass 1: per-(m-chunk, column) online max/sum partials
// pmx/psum layout: [b][mt][1024 cols] f32
__launch_bounds__(256)
__global__ void softmax_part(const float* __restrict__ attn,
                             float* __restrict__ pmx, float* __restrict__ psum)
{
    const int b   = blockIdx.z, mt = blockIdx.y;
    const int c   = threadIdx.x & 63;     // column quad within tile
    const int g   = threadIdx.x >> 6;     // m-subgroup (one per wave)
    const int col = blockIdx.x * 256 + c * 4;
    const float* a = attn + (long)b * (1023l * 1024) + col;

    const int m0   = mt * 128;
    const int mEnd = (m0 + 128 < 1023) ? m0 + 128 : 1023;

    float4 mx = make_float4(-1e30f, -1e30f, -1e30f, -1e30f);
    float4 sm = make_float4(0.f, 0.f, 0.f, 0.f);
    for (int m = m0 + g; m < mEnd; m += 4) {
        float4 v = *(const float4*)(a + (long)m * 1024);
        onl_upd(v.x, mx.x, sm.x); onl_upd(v.y, mx.y, sm.y);
        onl_upd(v.z, mx.z, sm.z); onl_upd(v.w, mx.w, sm.w);
    }

    __shared__ float4 lmx[4][64], lsm[4][64];
    lmx[g][c] = mx; lsm[g][c] = sm;
    __syncthreads();
    if (g == 0) {
        float4 MX = lmx[0][c], SM = lsm[0][c];
        #pragma unroll
        for (int gg = 1; gg < 4; gg++) {
            float4 omx = lmx[gg][c], osm = lsm[gg][c];
            onl_merge(MX.x, SM.x, omx.x, osm.x);
            onl_merge(MX.y, SM.y, omx.y, osm.y);
            onl_merge(MX.z, SM.z, omx.z, osm.z);
            onl_merge(MX.w, SM.w, omx.w, osm.w);
        }
        const long po = ((long)b * 8 + mt) * 1024 + col;
        *(float4*)(pmx + po)  = MX;
        *(float4*)(psum + po) = SM;
    }
}

// pass 2: merge the 8 partials per column, normalize this block's m-chunk,
// write bf16 soft [m][t]; row 1023 zeroed (K-padding for the A1 gemm)
__launch_bounds__(256)
__global__ void softmax_norm(const float* __restrict__ attn,
                             const float* __restrict__ pmx,
                             const float* __restrict__ psum,
                             bf16* __restrict__ soft)
{
    const int b   = blockIdx.z, mt = blockIdx.y;
    const int c   = threadIdx.x & 63;
    const int g   = threadIdx.x >> 6;
    const int col = blockIdx.x * 256 + c * 4;
    const float* a = attn + (long)b * (1023l * 1024) + col;
    bf16* s        = soft + (long)b * (1024l * 1024) + col;

    float4 MX = make_float4(-1e30f, -1e30f, -1e30f, -1e30f);
    float4 SM = make_float4(0.f, 0.f, 0.f, 0.f);
    #pragma unroll
    for (int t = 0; t < 8; t++) {
        const long po = ((long)b * 8 + t) * 1024 + col;
        float4 omx = *(const float4*)(pmx + po);
        float4 osm = *(const float4*)(psum + po);
        onl_merge(MX.x, SM.x, omx.x, osm.x);
        onl_merge(MX.y, SM.y, omx.y, osm.y);
        onl_merge(MX.z, SM.z, omx.z, osm.z);
        onl_merge(MX.w, SM.w, omx.w, osm.w);
    }
    const float4 INV = make_float4(1.f / SM.x, 1.f / SM.y, 1.f / SM.z, 1.f / SM.w);

    const int m0   = mt * 128;
    const int mEnd = (m0 + 128 < 1023) ? m0 + 128 : 1023;
    for (int m = m0 + g; m < mEnd; m += 4) {
        float4 v = *(const float4*)(a + (long)m * 1024);
        bf16x4 o;
        o[0] = (bf16)(__expf(v.x - MX.x) * INV.x);
        o[1] = (bf16)(__expf(v.y - MX.y) * INV.y);
        o[2] = (bf16)(__expf(v.z - MX.z) * INV.z);
        o[3] = (bf16)(__expf(v.w - MX.w) * INV.w);
        *(bf16x4*)(s + (long)m * 1024) = o;
    }
    if (mt == 7 && g == 3) {               // pad row 1023 with zeros (wave-uniform branch)
        bf16x4 z = {(bf16)0.f, (bf16)0.f, (bf16)0.f, (bf16)0.f};
        *(bf16x4*)(s + 1023l * 1024) = z;
    }
}

extern "C" void kernel_launch(void* const* d_in, const int* in_sizes, int n_in,
                              void* d_out, int out_size, void* d_ws, size_t ws_size,
                              hipStream_t stream)
{
    const float* xs    = (const float*)d_in[0];  // (32,512,1024) f32
    const float* W_emb = (const float*)d_in[1];  // (1024,512)
    const float* W_KQ  = (const float*)d_in[2];  // (1024,1024)
    const float* W_PV  = (const float*)d_in[3];  // (1024,1024)
    const float* W_un  = (const float*)d_in[4];  // (512,1024)
    const float* b_un  = (const float*)d_in[5];  // (512,)

    float* out  = (float*)d_out;                   // (32,512,1024) f32
    float* attn = out + (size_t)32 * 512 * 1024;   // (32,1023,1024) f32

    const long MB = 1024l * 1024;

    // workspace layout (bytes), bf16 buffers
    char* ws = (char*)d_ws;
    const size_t oXsT  = 0;                        // 32*1024*512*2 = 33.5 MB
    const size_t oET   = oXsT + (size_t)33554432;  // 64 MB each below
    const size_t oEn   = oET  + (size_t)67108864;
    const size_t oQT   = oEn  + (size_t)67108864;
    const size_t oR    = oQT  + (size_t)67108864;
    const size_t oWe   = oR   + (size_t)67108864;  // weights bf16: 1+2+2+1 MB
    const size_t oWkq  = oWe  + (size_t)1048576;
    const size_t oWpv  = oWkq + (size_t)2097152;
    const size_t oWun  = oWpv + (size_t)2097152;
    const size_t need  = oWun + (size_t)1048576;
    if (ws_size < need) { fprintf(stderr, "ws too small: %zu < %zu\n", ws_size, need); return; }

    bf16* xsT   = (bf16*)(ws + oXsT);
    bf16* ET    = (bf16*)(ws + oET);
    bf16* En    = (bf16*)(ws + oEn);
    bf16* QT    = (bf16*)(ws + oQT);
    bf16* R     = (bf16*)(ws + oR);
    bf16* We    = (bf16*)(ws + oWe);
    bf16* Wkq   = (bf16*)(ws + oWkq);
    bf16* Wpv   = (bf16*)(ws + oWpv);
    bf16* Wun   = (bf16*)(ws + oWun);
    bf16* soft  = ET;   // reuse: ET dead after attn gemm
    bf16* softT = QT;   // reuse: QT dead after attn gemm
    bf16* A1T   = R;
    bf16* fT    = ET;   // reuse: soft dead after its transpose

    // softmax partials live in R's space (R/A1T is first written AFTER softmax)
    float* pmx  = (float*)(ws + oR);               // 32*8*1024 f32 = 1 MB
    float* psum = pmx + (size_t)32 * 8 * 1024;     // +1 MB

    const dim3 tb(32, 8);
    const int BIG = 1 << 30;

    // weight converts f32 -> bf16
    cvt_f32_bf16<<<512, 256, 0, stream>>>(W_emb, We, 524288);
    cvt_f32_bf16<<<1024, 256, 0, stream>>>(W_KQ, Wkq, 1048576);
    cvt_f32_bf16<<<1024, 256, 0, stream>>>(W_PV, Wpv, 1048576);
    cvt_f32_bf16<<<512, 256, 0, stream>>>(W_un, Wun, 524288);
    // xs (512x1024 f32) -> xsT (1024x512 bf16), per batch
    transpose_f32_bf16<<<dim3(32, 16, 32), tb, 0, stream>>>(xs, xsT, 512, 1024);
    // E^T[t][d] = sum_n xsT[t][n] * We[d][n] + sinusoid(t,d)
    gemm_nt<EPI_SINUS, bf16><<<dim3(8, 8, 32), 256, 0, stream>>>(
        xsT, 512l * 1024, 512, We, 0, 512, ET, MB, 1024, 512, BIG, nullptr);
    // E^T -> E (natural [e][m])
    transpose_bf16<<<dim3(32, 32, 32), tb, 0, stream>>>(ET, En, 1024, 1024);
    // Q^T[t][d] = sum_e E^T[t][e] * Wkq[d][e]
    gemm_nt<EPI_NONE, bf16><<<dim3(8, 8, 32), 256, 0, stream>>>(
        ET, MB, 1024, Wkq, 0, 1024, QT, MB, 1024, 1024, BIG, nullptr);
    // attn[m][t] = sum_e E^T[m][e] * Q^T[t][e], rows m<1023, f32 -> d_out
    gemm_nt<EPI_NONE, float><<<dim3(8, 8, 32), 256, 0, stream>>>(
        ET, MB, 1024, QT, MB, 1024, attn, 1023l * 1024, 1024, 1024, 1023, nullptr);
    // column softmax over m: split-m partials then normalize (bf16 soft, row 1023 zeroed)
    softmax_part<<<dim3(4, 8, 32), 256, 0, stream>>>(attn, pmx, psum);
    softmax_norm<<<dim3(4, 8, 32), 256, 0, stream>>>(attn, pmx, psum, soft);
    // soft -> soft^T [t][m]
    transpose_bf16<<<dim3(32, 32, 32), tb, 0, stream>>>(soft, softT, 1024, 1024);
    // A1^T[t][e] = sum_m soft^T[t][m] * E[e][m]
    gemm_nt<EPI_NONE, bf16><<<dim3(8, 8, 32), 256, 0, stream>>>(
        softT, MB, 1024, En, MB, 1024, A1T, MB, 1024, 1024, BIG, nullptr);
    // f_attn^T[t][d] = sum_e A1^T[t][e] * Wpv[d][e]
    gemm_nt<EPI_NONE, bf16><<<dim3(8, 8, 32), 256, 0, stream>>>(
        A1T, MB, 1024, Wpv, 0, 1024, fT, MB, 1024, 1024, BIG, nullptr);
    // out[o][t] = sum_d Wun[o][d] * f_attn^T[t][d] + b_un[o], f32 -> d_out
    gemm_nt<EPI_BIAS, float><<<dim3(8, 4, 32), 256, 0, stream>>>(
        Wun, 0, 1024, fT, MB, 1024, out, 512l * 1024, 1024, 1024, BIG, b_un);
}

// Round 2
// 829.111 us; speedup vs baseline: 1.7594x; 1.1771x over previous
//
#include <hip/hip_runtime.h>
#include <hip/hip_bf16.h>
#include <cstdio>

typedef __bf16 bf16;
typedef __bf16 bf16x4 __attribute__((ext_vector_type(4)));
typedef __bf16 bf16x8 __attribute__((ext_vector_type(8)));
typedef float  f32x4  __attribute__((ext_vector_type(4)));

#define AS1 __attribute__((address_space(1)))
#define AS3 __attribute__((address_space(3)))

__device__ __forceinline__ void async16(void* lds, const void* g) {
    __builtin_amdgcn_global_load_lds((AS1 unsigned int*)g, (AS3 unsigned int*)lds, 16, 0, 0);
}

enum { EPI_NONE = 0, EPI_SINUS = 1, EPI_BIAS = 2 };

#define FENCE asm volatile("" ::: "memory")
#define BAR   do { FENCE; __builtin_amdgcn_s_barrier(); FENCE; } while (0)
#define LGKM0 do { asm volatile("s_waitcnt lgkmcnt(0)" ::: "memory"); \
                   __builtin_amdgcn_sched_barrier(0); } while (0)
#define RD8(p) (*(const bf16x8*)(const void*)(p))

// 16 MFMA: C-quadrant (MB..MB+3) x (NB..NB+1), K=64 (2 ksubs)
#define QUAD_MFMA(MB, NB)                                                      \
    _Pragma("unroll") for (int mf = 0; mf < 4; ++mf)                           \
    _Pragma("unroll") for (int nf = 0; nf < 2; ++nf)                           \
    _Pragma("unroll") for (int s = 0; s < 2; ++s)                              \
        acc[(MB) + mf][(NB) + nf] = __builtin_amdgcn_mfma_f32_16x16x32_bf16(   \
            af[(MB) + mf][s], bfr[(NB) + nf][s], acc[(MB) + mf][(NB) + nf], 0, 0, 0);

// ---------------- 256x256 8-phase NT GEMM (m201-style template) ----------------
// C[m][n] = sum_k A[m][k]*B[n][k], bf16 in, CT out. BM=BN=256, BK=64, 512 thr (8 waves 2Mx4N).
// LDS 128KB: A[2buf][2half][128][64] + B same. LDS XOR-swizzle byte^=((row&7)<<4) applied on
// BOTH the pre-swizzled global_load_lds source and the ds_read address (involution).
// Per K-tile: 4 phases {ds_read 12/8/4/0 || stage 1 half-tile -> bar -> lgkm0 -> 16 MFMA -> bar}.
// Stage schedule: P1:B0(t+1) P2:B1(t+1) P3:A0(t+2) P4:A1(t+2); single counted vmcnt(4) at P4
// (waits tile t+1 fully resident; leaves A halves of t+2 in flight). Never vmcnt(0) mid-loop.
template <int EPI, typename CT>
__launch_bounds__(512, 2)
__global__ void gemm8(const bf16* __restrict__ A, long sA, int lda,
                      const bf16* __restrict__ B, long sB, int ldb,
                      CT* __restrict__ C, long sC, int ldc,
                      int K, int mLimit, const float* __restrict__ bias,
                      int tilesM, int tilesN)
{
    __shared__ __align__(16) char smem[131072];
    char* ldsA = smem;
    char* ldsB = smem + 65536;

    const int tid  = threadIdx.x;
    const int wave = tid >> 6;
    const int lane = tid & 63;
    const int quad = lane >> 4;
    const int l16  = lane & 15;
    const int hw   = wave >> 2;        // wave's A half (M strip)
    const int wq   = wave & 3;         // wave's N strip (64 cols)
    const int hbB  = wq >> 1;          // wave's B half
    const int rrB  = (wq & 1) * 64;    // row base within B half

    // T1: bijective XCD-chunked swizzle; consecutive wgid -> same XCD, whole batches per chunk
    const int nwg = gridDim.x;
    const int qq = nwg >> 3, rr = nwg & 7;
    const int xcd = blockIdx.x & 7, idx = blockIdx.x >> 3;
    const int wgid = (xcd < rr ? xcd * (qq + 1) : rr * (qq + 1) + (xcd - rr) * qq) + idx;

    const int tpb = tilesM * tilesN;
    const int b   = wgid / tpb;
    const int rem = wgid - b * tpb;
    const int m0  = (rem / tilesN) * 256;
    const int n0  = (rem % tilesN) * 256;

    A += (long)b * sA;
    B += (long)b * sB;

    // staging: dest (linear) od = wave*1024 + lane*16 (+ j*8192); source pre-swizzled so that
    // LDS[od] = G[od ^ ((destrow&7)<<4)]  (swz touches bits 4-6 only; row bits 7-9 unchanged)
    const int odt  = wave * 1024 + lane * 16;
    const int ol   = odt ^ (((odt >> 7) & 7) << 4);
    const int srow = ol >> 7;            // 0..63 (issue j=1 adds 64)
    const int scol = (ol & 127) >> 1;    // element col, multiple of 8
    const bf16* pA = A + (long)(m0 + srow) * lda + scol;
    const bf16* pB = B + (long)(n0 + srow) * ldb + scol;

    // ds_read lane offsets: logical (row*128 + s*64 + quad*16) ^ ((row&7)<<4); row&7 == l16&7
    const int xr = (l16 & 7) << 4;
    const int lane2_0 = ((l16 * 128) + (quad * 16)) ^ xr;
    const int lane2_1 = ((l16 * 128) + 64 + (quad * 16)) ^ xr;

    auto stgA = [&](int bb, int h, int kt) {
        char* l = ldsA + bb * 32768 + h * 16384 + wave * 1024;
        const bf16* g = pA + (long)(h * 128) * lda + kt * 64;
        async16(l, g);
        async16(l + 8192, g + (long)64 * lda);
    };
    auto stgB = [&](int bb, int h, int kt) {
        char* l = ldsB + bb * 32768 + h * 16384 + wave * 1024;
        const bf16* g = pB + (long)(h * 128) * ldb + kt * 64;
        async16(l, g);
        async16(l + 8192, g + (long)64 * ldb);
    };

    const int nk = K >> 6;

    // prologue: tile0 all 4 halves + A halves of tile1; vmcnt(4) leaves A(1) in flight
    stgA(0, 0, 0); stgA(0, 1, 0);
    stgB(0, 0, 0); stgB(0, 1, 0);
    stgA(1, 0, 1); stgA(1, 1, 1);
    asm volatile("s_waitcnt vmcnt(4)" ::: "memory");
    BAR;

    bf16x8 af[8][2], bfr[4][2];
    f32x4 acc[8][4] = {};

    for (int t = 0; t < nk; ++t) {
        const int cur = t & 1;
        const char* aH = ldsA + cur * 32768 + hw * 16384;
        const char* bH = ldsB + cur * 32768 + hbB * 16384 + rrB * 128;

        // ---- P1: af[0..3] + bfr[0..1] (12 ds_reads) || stage B0(t+1) ----
        #pragma unroll
        for (int mf = 0; mf < 4; ++mf) {
            af[mf][0] = RD8(aH + mf * 2048 + lane2_0);
            af[mf][1] = RD8(aH + mf * 2048 + lane2_1);
        }
        #pragma unroll
        for (int nf = 0; nf < 2; ++nf) {
            bfr[nf][0] = RD8(bH + nf * 2048 + lane2_0);
            bfr[nf][1] = RD8(bH + nf * 2048 + lane2_1);
        }
        if (t + 1 < nk) stgB(cur ^ 1, 0, t + 1);
        BAR;
        LGKM0;
        __builtin_amdgcn_s_setprio(1);
        QUAD_MFMA(0, 0);
        __builtin_amdgcn_s_setprio(0);
        BAR;

        // ---- P2: af[4..7] (8 ds_reads) || stage B1(t+1) ----
        #pragma unroll
        for (int mf = 4; mf < 8; ++mf) {
            af[mf][0] = RD8(aH + mf * 2048 + lane2_0);
            af[mf][1] = RD8(aH + mf * 2048 + lane2_1);
        }
        if (t + 1 < nk) stgB(cur ^ 1, 1, t + 1);
        BAR;
        LGKM0;
        __builtin_amdgcn_s_setprio(1);
        QUAD_MFMA(4, 0);
        __builtin_amdgcn_s_setprio(0);
        BAR;

        // ---- P3: bfr[2..3] (4 ds_reads) || stage A0(t+2) (A region of cur is dead) ----
        #pragma unroll
        for (int nf = 2; nf < 4; ++nf) {
            bfr[nf][0] = RD8(bH + nf * 2048 + lane2_0);
            bfr[nf][1] = RD8(bH + nf * 2048 + lane2_1);
        }
        if (t + 2 < nk) stgA(cur, 0, t + 2);
        BAR;
        LGKM0;
        __builtin_amdgcn_s_setprio(1);
        QUAD_MFMA(4, 2);
        __builtin_amdgcn_s_setprio(0);
        BAR;

        // ---- P4: no ds_reads || stage A1(t+2); counted vmcnt ----
        if (t + 2 < nk) {
            stgA(cur, 1, t + 2);
            asm volatile("s_waitcnt vmcnt(4)" ::: "memory");   // tile t+1 resident; A(t+2) in flight
        } else {
            asm volatile("s_waitcnt vmcnt(0)" ::: "memory");   // epilogue drain
        }
        BAR;
        __builtin_amdgcn_s_setprio(1);
        QUAD_MFMA(0, 2);
        __builtin_amdgcn_s_setprio(0);
        BAR;
    }

    C += (long)b * sC;

    #pragma unroll
    for (int nf = 0; nf < 4; ++nf) {
        const int col = n0 + wq * 64 + nf * 16 + l16;
        float fr = 0.f;
        if (EPI == EPI_SINUS)
            fr = __expf((float)(-(col & ~1)) * (9.210340371976184f / 1024.f)); // exp(-(2i)ln(1e4)/d)
        #pragma unroll
        for (int mf = 0; mf < 8; ++mf) {
            #pragma unroll
            for (int r = 0; r < 4; ++r) {
                const int row = m0 + hw * 128 + mf * 16 + quad * 4 + r; // C/D: row=quad*4+reg, col=l16
                float v = acc[mf][nf][r];
                if (EPI == EPI_SINUS) {
                    float ang = (float)row * fr;
                    v += (col & 1) ? __cosf(ang) : __sinf(ang);
                }
                if (EPI == EPI_BIAS) v += bias[row];
                if (row < mLimit)
                    C[(long)row * ldc + col] = (CT)v;
            }
        }
    }
}

// f32 -> bf16 flat convert (n % 4 == 0)
__launch_bounds__(256)
__global__ void cvt_f32_bf16(const float* __restrict__ in, bf16* __restrict__ out, int n)
{
    int i = (blockIdx.x * 256 + threadIdx.x) * 4;
    if (i < n) {
        float4 v = *(const float4*)(in + i);
        out[i]     = (bf16)v.x;
        out[i + 1] = (bf16)v.y;
        out[i + 2] = (bf16)v.z;
        out[i + 3] = (bf16)v.w;
    }
}

// batched transpose + f32->bf16: in (rows x cols) f32 -> out (cols x rows) bf16
__launch_bounds__(256)
__global__ void transpose_f32_bf16(const float* __restrict__ in, bf16* __restrict__ out,
                                   int rows, int cols)
{
    __shared__ float tile[32][33];
    const long bs = (long)rows * cols;
    in  += (long)blockIdx.z * bs;
    out += (long)blockIdx.z * bs;
    const int c0 = blockIdx.x * 32, r0 = blockIdx.y * 32;
    const int tx = threadIdx.x, ty = threadIdx.y;
    #pragma unroll
    for (int i = ty; i < 32; i += 8)
        tile[i][tx] = in[(long)(r0 + i) * cols + c0 + tx];
    __syncthreads();
    #pragma unroll
    for (int i = ty; i < 32; i += 8)
        out[(long)(c0 + i) * rows + r0 + tx] = (bf16)tile[tx][i];
}

// batched bf16 transpose: in (rows x cols) -> out (cols x rows)
__launch_bounds__(256)
__global__ void transpose_bf16(const bf16* __restrict__ in, bf16* __restrict__ out,
                               int rows, int cols)
{
    __shared__ bf16 tile[32][33];
    const long bs = (long)rows * cols;
    in  += (long)blockIdx.z * bs;
    out += (long)blockIdx.z * bs;
    const int c0 = blockIdx.x * 32, r0 = blockIdx.y * 32;
    const int tx = threadIdx.x, ty = threadIdx.y;
    #pragma unroll
    for (int i = ty; i < 32; i += 8)
        tile[i][tx] = in[(long)(r0 + i) * cols + c0 + tx];
    __syncthreads();
    #pragma unroll
    for (int i = ty; i < 32; i += 8)
        out[(long)(c0 + i) * rows + r0 + tx] = tile[tx][i];
}

// ---------- column softmax over m of attn (f32, (1023,1024) per batch) ----------
__device__ __forceinline__ void onl_upd(float v, float& mx, float& sm) {
    if (v > mx) { sm = sm * __expf(mx - v) + 1.f; mx = v; }
    else        { sm += __expf(v - mx); }
}

__device__ __forceinline__ void onl_merge(float& mx, float& sm, float omx, float osm) {
    float nm = fmaxf(mx, omx);
    sm = sm * __expf(mx - nm) + osm * __expf(omx - nm);
    mx = nm;
}

// pass 1: per-(m-chunk, column) online max/sum partials; pmx/psum: [b][mt][1024] f32
__launch_bounds__(256)
__global__ void softmax_part(const float* __restrict__ attn,
                             float* __restrict__ pmx, float* __restrict__ psum)
{
    const int b   = blockIdx.z, mt = blockIdx.y;
    const int c   = threadIdx.x & 63;
    const int g   = threadIdx.x >> 6;
    const int col = blockIdx.x * 256 + c * 4;
    const float* a = attn + (long)b * (1023l * 1024) + col;

    const int m0   = mt * 128;
    const int mEnd = (m0 + 128 < 1023) ? m0 + 128 : 1023;

    float4 mx = make_float4(-1e30f, -1e30f, -1e30f, -1e30f);
    float4 sm = make_float4(0.f, 0.f, 0.f, 0.f);
    for (int m = m0 + g; m < mEnd; m += 4) {
        float4 v = *(const float4*)(a + (long)m * 1024);
        onl_upd(v.x, mx.x, sm.x); onl_upd(v.y, mx.y, sm.y);
        onl_upd(v.z, mx.z, sm.z); onl_upd(v.w, mx.w, sm.w);
    }

    __shared__ float4 lmx[4][64], lsm[4][64];
    lmx[g][c] = mx; lsm[g][c] = sm;
    __syncthreads();
    if (g == 0) {
        float4 MX = lmx[0][c], SM = lsm[0][c];
        #pragma unroll
        for (int gg = 1; gg < 4; gg++) {
            float4 omx = lmx[gg][c], osm = lsm[gg][c];
            onl_merge(MX.x, SM.x, omx.x, osm.x);
            onl_merge(MX.y, SM.y, omx.y, osm.y);
            onl_merge(MX.z, SM.z, omx.z, osm.z);
            onl_merge(MX.w, SM.w, omx.w, osm.w);
        }
        const long po = ((long)b * 8 + mt) * 1024 + col;
        *(float4*)(pmx + po)  = MX;
        *(float4*)(psum + po) = SM;
    }
}

// pass 2: merge 8 partials per column, normalize this m-chunk, write bf16; row 1023 zeroed
__launch_bounds__(256)
__global__ void softmax_norm(const float* __restrict__ attn,
                             const float* __restrict__ pmx,
                             const float* __restrict__ psum,
                             bf16* __restrict__ soft)
{
    const int b   = blockIdx.z, mt = blockIdx.y;
    const int c   = threadIdx.x & 63;
    const int g   = threadIdx.x >> 6;
    const int col = blockIdx.x * 256 + c * 4;
    const float* a = attn + (long)b * (1023l * 1024) + col;
    bf16* s        = soft + (long)b * (1024l * 1024) + col;

    float4 MX = make_float4(-1e30f, -1e30f, -1e30f, -1e30f);
    float4 SM = make_float4(0.f, 0.f, 0.f, 0.f);
    #pragma unroll
    for (int t = 0; t < 8; t++) {
        const long po = ((long)b * 8 + t) * 1024 + col;
        float4 omx = *(const float4*)(pmx + po);
        float4 osm = *(const float4*)(psum + po);
        onl_merge(MX.x, SM.x, omx.x, osm.x);
        onl_merge(MX.y, SM.y, omx.y, osm.y);
        onl_merge(MX.z, SM.z, omx.z, osm.z);
        onl_merge(MX.w, SM.w, omx.w, osm.w);
    }
    const float4 INV = make_float4(1.f / SM.x, 1.f / SM.y, 1.f / SM.z, 1.f / SM.w);

    const int m0   = mt * 128;
    const int mEnd = (m0 + 128 < 1023) ? m0 + 128 : 1023;
    for (int m = m0 + g; m < mEnd; m += 4) {
        float4 v = *(const float4*)(a + (long)m * 1024);
        bf16x4 o;
        o[0] = (bf16)(__expf(v.x - MX.x) * INV.x);
        o[1] = (bf16)(__expf(v.y - MX.y) * INV.y);
        o[2] = (bf16)(__expf(v.z - MX.z) * INV.z);
        o[3] = (bf16)(__expf(v.w - MX.w) * INV.w);
        *(bf16x4*)(s + (long)m * 1024) = o;
    }
    if (mt == 7 && g == 3) {
        bf16x4 z = {(bf16)0.f, (bf16)0.f, (bf16)0.f, (bf16)0.f};
        *(bf16x4*)(s + 1023l * 1024) = z;
    }
}

extern "C" void kernel_launch(void* const* d_in, const int* in_sizes, int n_in,
                              void* d_out, int out_size, void* d_ws, size_t ws_size,
                              hipStream_t stream)
{
    const float* xs    = (const float*)d_in[0];  // (32,512,1024) f32
    const float* W_emb = (const float*)d_in[1];  // (1024,512)
    const float* W_KQ  = (const float*)d_in[2];  // (1024,1024)
    const float* W_PV  = (const float*)d_in[3];  // (1024,1024)
    const float* W_un  = (const float*)d_in[4];  // (512,1024)
    const float* b_un  = (const float*)d_in[5];  // (512,)

    float* out  = (float*)d_out;                   // (32,512,1024) f32
    float* attn = out + (size_t)32 * 512 * 1024;   // (32,1023,1024) f32

    const long MB = 1024l * 1024;

    // workspace layout (bytes), bf16 buffers
    char* ws = (char*)d_ws;
    const size_t oXsT  = 0;                        // 32*1024*512*2 = 33.5 MB
    const size_t oET   = oXsT + (size_t)33554432;  // 64 MB each below
    const size_t oEn   = oET  + (size_t)67108864;
    const size_t oQT   = oEn  + (size_t)67108864;
    const size_t oR    = oQT  + (size_t)67108864;
    const size_t oWe   = oR   + (size_t)67108864;  // weights bf16: 1+2+2+1 MB
    const size_t oWkq  = oWe  + (size_t)1048576;
    const size_t oWpv  = oWkq + (size_t)2097152;
    const size_t oWun  = oWpv + (size_t)2097152;
    const size_t need  = oWun + (size_t)1048576;
    if (ws_size < need) { fprintf(stderr, "ws too small: %zu < %zu\n", ws_size, need); return; }

    bf16* xsT   = (bf16*)(ws + oXsT);
    bf16* ET    = (bf16*)(ws + oET);
    bf16* En    = (bf16*)(ws + oEn);
    bf16* QT    = (bf16*)(ws + oQT);
    bf16* R     = (bf16*)(ws + oR);
    bf16* We    = (bf16*)(ws + oWe);
    bf16* Wkq   = (bf16*)(ws + oWkq);
    bf16* Wpv   = (bf16*)(ws + oWpv);
    bf16* Wun   = (bf16*)(ws + oWun);
    bf16* soft  = ET;   // reuse: ET dead after attn gemm
    bf16* softT = QT;   // reuse: QT dead after attn gemm
    bf16* A1T   = R;
    bf16* fT    = ET;   // reuse: soft dead after its transpose

    // softmax partials live in R's space (R/A1T is first written AFTER softmax)
    float* pmx  = (float*)(ws + oR);               // 32*8*1024 f32 = 1 MB
    float* psum = pmx + (size_t)32 * 8 * 1024;     // +1 MB

    const dim3 tb(32, 8);
    const int BIG = 1 << 30;

    // weight converts f32 -> bf16
    cvt_f32_bf16<<<512, 256, 0, stream>>>(W_emb, We, 524288);
    cvt_f32_bf16<<<1024, 256, 0, stream>>>(W_KQ, Wkq, 1048576);
    cvt_f32_bf16<<<1024, 256, 0, stream>>>(W_PV, Wpv, 1048576);
    cvt_f32_bf16<<<512, 256, 0, stream>>>(W_un, Wun, 524288);
    // xs (512x1024 f32) -> xsT (1024x512 bf16), per batch
    transpose_f32_bf16<<<dim3(32, 16, 32), tb, 0, stream>>>(xs, xsT, 512, 1024);
    // E^T[t][d] = sum_n xsT[t][n] * We[d][n] + sinusoid(t,d)
    gemm8<EPI_SINUS, bf16><<<dim3(512), 512, 0, stream>>>(
        xsT, 512l * 1024, 512, We, 0, 512, ET, MB, 1024, 512, BIG, nullptr, 4, 4);
    // E^T -> E (natural [e][m])
    transpose_bf16<<<dim3(32, 32, 32), tb, 0, stream>>>(ET, En, 1024, 1024);
    // Q^T[t][d] = sum_e E^T[t][e] * Wkq[d][e]
    gemm8<EPI_NONE, bf16><<<dim3(512), 512, 0, stream>>>(
        ET, MB, 1024, Wkq, 0, 1024, QT, MB, 1024, 1024, BIG, nullptr, 4, 4);
    // attn[m][t] = sum_e E^T[m][e] * Q^T[t][e], rows m<1023, f32 -> d_out
    gemm8<EPI_NONE, float><<<dim3(512), 512, 0, stream>>>(
        ET, MB, 1024, QT, MB, 1024, attn, 1023l * 1024, 1024, 1024, 1023, nullptr, 4, 4);
    // column softmax over m: split-m partials then normalize (bf16 soft, row 1023 zeroed)
    softmax_part<<<dim3(4, 8, 32), 256, 0, stream>>>(attn, pmx, psum);
    softmax_norm<<<dim3(4, 8, 32), 256, 0, stream>>>(attn, pmx, psum, soft);
    // soft -> soft^T [t][m]
    transpose_bf16<<<dim3(32, 32, 32), tb, 0, stream>>>(soft, softT, 1024, 1024);
    // A1^T[t][e] = sum_m soft^T[t][m] * E[e][m]
    gemm8<EPI_NONE, bf16><<<dim3(512), 512, 0, stream>>>(
        softT, MB, 1024, En, MB, 1024, A1T, MB, 1024, 1024, BIG, nullptr, 4, 4);
    // f_attn^T[t][d] = sum_e A1^T[t][e] * Wpv[d][e]
    gemm8<EPI_NONE, bf16><<<dim3(512), 512, 0, stream>>>(
        A1T, MB, 1024, Wpv, 0, 1024, fT, MB, 1024, 1024, BIG, nullptr, 4, 4);
    // out[o][t] = sum_d Wun[o][d] * f_attn^T[t][d] + b_un[o], f32 -> d_out
    gemm8<EPI_BIAS, float><<<dim3(256), 512, 0, stream>>>(
        Wun, 0, 1024, fT, MB, 1024, out, 512l * 1024, 1024, 1024, BIG, b_un, 2, 4);
}

// Round 3
// 801.114 us; speedup vs baseline: 1.8209x; 1.0349x over previous
//
#include <hip/hip_runtime.h>
#include <hip/hip_bf16.h>
#include <cstdio>

typedef __bf16 bf16;
typedef __bf16 bf16x4 __attribute__((ext_vector_type(4)));
typedef __bf16 bf16x8 __attribute__((ext_vector_type(8)));
typedef float  f32x4  __attribute__((ext_vector_type(4)));

#define AS1 __attribute__((address_space(1)))
#define AS3 __attribute__((address_space(3)))

__device__ __forceinline__ void async16(void* lds, const void* g) {
    __builtin_amdgcn_global_load_lds((AS1 unsigned int*)g, (AS3 unsigned int*)lds, 16, 0, 0);
}

enum { EPI_NONE = 0, EPI_SINUS = 1, EPI_BIAS = 2, EPI_ATTN = 3 };

#define FENCE asm volatile("" ::: "memory")
#define BAR   do { FENCE; __builtin_amdgcn_s_barrier(); FENCE; } while (0)
#define LGKM0 do { asm volatile("s_waitcnt lgkmcnt(0)" ::: "memory"); \
                   __builtin_amdgcn_sched_barrier(0); } while (0)
#define RD8(p) (*(const bf16x8*)(const void*)(p))

// 16 MFMA: quadrant rows (MB..MB+3) x cols (NB..NB+1), K=64 (2 ksubs)
#define MFMA_Q(AF, MB, BF, NB)                                                 \
    _Pragma("unroll") for (int mf = 0; mf < 4; ++mf)                           \
    _Pragma("unroll") for (int nf = 0; nf < 2; ++nf)                           \
    _Pragma("unroll") for (int s = 0; s < 2; ++s)                              \
        acc[(MB) + mf][(NB) + nf] = __builtin_amdgcn_mfma_f32_16x16x32_bf16(   \
            AF[mf][s], BF[nf][s], acc[(MB) + mf][(NB) + nf], 0, 0, 0);

__device__ __forceinline__ void onl_merge(float& mx, float& sm, float omx, float osm) {
    float nm = fmaxf(mx, omx);
    sm = sm * __expf(mx - nm) + osm * __expf(omx - nm);
    mx = nm;
}

// ---------------- 256x256 8-phase NT GEMM (m201-style template) ----------------
// C[m][n] = sum_k A[m][k]*B[n][k], bf16 in, CT out. BM=BN=256, BK=64, 512 thr (8 waves 2Mx4N).
// LDS 128KB: A[2buf][2half][128][64] + B same. XOR-swizzle byte^=((row&7)<<4) on BOTH the
// pre-swizzled global_load_lds source and the ds_read address (involution, conflict-free).
// Quadrant order (0,0)->(0,2)->(4,0)->(4,2) keeps fragment liveness low (af03 dead after P2,
// af47 read in P3): peak live ~= acc128 + 64 frag + addr ~ 212 VGPR (no spill at the 256 cap).
// Stage schedule: P1:B0(t+1) P2:B1(t+1) P3:A0(t+2) P4:A1(t+2); single counted vmcnt(4) at P4.
// EPI_ATTN: epilogue additionally reduces per-column (max, sum-exp) over the block's 256 rows
// (shfl quad-merge + LDS cross-wave merge) -> partials [b][4 mtiles][1024 cols].
template <int EPI, typename CT>
__launch_bounds__(512, 2)
__global__ void gemm8(const bf16* __restrict__ A, long sA, int lda,
                      const bf16* __restrict__ B, long sB, int ldb,
                      CT* __restrict__ C, long sC, int ldc,
                      int K, int mLimit, const float* __restrict__ bias,
                      float* __restrict__ pmx, float* __restrict__ psum,
                      int tilesM, int tilesN)
{
    __shared__ __align__(16) char smem[131072];
    char* ldsA = smem;
    char* ldsB = smem + 65536;

    const int tid  = threadIdx.x;
    const int wave = tid >> 6;
    const int lane = tid & 63;
    const int quad = lane >> 4;
    const int l16  = lane & 15;
    const int hw   = wave >> 2;        // wave's A half (M strip)
    const int wq   = wave & 3;         // wave's N strip (64 cols)
    const int hbB  = wq >> 1;          // wave's B half
    const int rrB  = (wq & 1) * 64;    // row base within B half

    // T1: bijective XCD-chunked swizzle; consecutive wgid -> same XCD, whole batches per chunk
    const int nwg = gridDim.x;
    const int qq = nwg >> 3, rr = nwg & 7;
    const int xcd = blockIdx.x & 7, idx = blockIdx.x >> 3;
    const int wgid = (xcd < rr ? xcd * (qq + 1) : rr * (qq + 1) + (xcd - rr) * qq) + idx;

    const int tpb = tilesM * tilesN;
    const int b   = wgid / tpb;
    const int rem = wgid - b * tpb;
    const int m0  = (rem / tilesN) * 256;
    const int n0  = (rem % tilesN) * 256;

    A += (long)b * sA;
    B += (long)b * sB;

    // staging: dest (linear) od = wave*1024 + lane*16 (+ j*8192); source pre-swizzled so that
    // LDS[od] = G[od ^ ((destrow&7)<<4)]  (swz touches bits 4-6 only; row bits 7-9 unchanged)
    const int odt  = wave * 1024 + lane * 16;
    const int ol   = odt ^ (((odt >> 7) & 7) << 4);
    const int srow = ol >> 7;            // 0..63 (issue j=1 adds 64)
    const int scol = (ol & 127) >> 1;    // element col, multiple of 8
    const bf16* pA = A + (long)(m0 + srow) * lda + scol;
    const bf16* pB = B + (long)(n0 + srow) * ldb + scol;

    // ds_read lane offsets: logical (row*128 + s*64 + quad*16) ^ ((row&7)<<4); row&7 == l16&7
    const int xr = (l16 & 7) << 4;
    const int lane2_0 = ((l16 * 128) + (quad * 16)) ^ xr;
    const int lane2_1 = ((l16 * 128) + 64 + (quad * 16)) ^ xr;

    auto stgA = [&](int bb, int h, int kt) {
        char* l = ldsA + bb * 32768 + h * 16384 + wave * 1024;
        const bf16* g = pA + (long)(h * 128) * lda + kt * 64;
        async16(l, g);
        async16(l + 8192, g + (long)64 * lda);
    };
    auto stgB = [&](int bb, int h, int kt) {
        char* l = ldsB + bb * 32768 + h * 16384 + wave * 1024;
        const bf16* g = pB + (long)(h * 128) * ldb + kt * 64;
        async16(l, g);
        async16(l + 8192, g + (long)64 * ldb);
    };

    const int nk = K >> 6;

    // prologue: tile0 all 4 halves + A halves of tile1; vmcnt(4) leaves A(1) in flight
    stgA(0, 0, 0); stgA(0, 1, 0);
    stgB(0, 0, 0); stgB(0, 1, 0);
    stgA(1, 0, 1); stgA(1, 1, 1);
    asm volatile("s_waitcnt vmcnt(4)" ::: "memory");
    BAR;

    f32x4 acc[8][4] = {};

    for (int t = 0; t < nk; ++t) {
        const int cur = t & 1;
        const char* aH = ldsA + cur * 32768 + hw * 16384;
        const char* bH = ldsB + cur * 32768 + hbB * 16384 + rrB * 128;

        bf16x8 af03[4][2], af47[4][2], bf01[2][2], bf23[2][2];

        // ---- P1: af03 (8) + bf01 (4) || stage B0(t+1) ----
        #pragma unroll
        for (int mf = 0; mf < 4; ++mf) {
            af03[mf][0] = RD8(aH + mf * 2048 + lane2_0);
            af03[mf][1] = RD8(aH + mf * 2048 + lane2_1);
        }
        #pragma unroll
        for (int nf = 0; nf < 2; ++nf) {
            bf01[nf][0] = RD8(bH + nf * 2048 + lane2_0);
            bf01[nf][1] = RD8(bH + nf * 2048 + lane2_1);
        }
        if (t + 1 < nk) stgB(cur ^ 1, 0, t + 1);
        BAR;
        LGKM0;
        __builtin_amdgcn_s_setprio(1);
        MFMA_Q(af03, 0, bf01, 0);
        __builtin_amdgcn_s_setprio(0);
        BAR;

        // ---- P2: bf23 (4) || stage B1(t+1) ----
        #pragma unroll
        for (int nf = 0; nf < 2; ++nf) {
            bf23[nf][0] = RD8(bH + (nf + 2) * 2048 + lane2_0);
            bf23[nf][1] = RD8(bH + (nf + 2) * 2048 + lane2_1);
        }
        if (t + 1 < nk) stgB(cur ^ 1, 1, t + 1);
        BAR;
        LGKM0;
        __builtin_amdgcn_s_setprio(1);
        MFMA_Q(af03, 0, bf23, 2);          // af03 dead after this
        __builtin_amdgcn_s_setprio(0);
        BAR;

        // ---- P3: af47 (8) || stage A0(t+2) (A region of cur is dead) ----
        #pragma unroll
        for (int mf = 0; mf < 4; ++mf) {
            af47[mf][0] = RD8(aH + (mf + 4) * 2048 + lane2_0);
            af47[mf][1] = RD8(aH + (mf + 4) * 2048 + lane2_1);
        }
        if (t + 2 < nk) stgA(cur, 0, t + 2);
        BAR;
        LGKM0;
        __builtin_amdgcn_s_setprio(1);
        MFMA_Q(af47, 4, bf01, 0);          // bf01 dead after this
        __builtin_amdgcn_s_setprio(0);
        BAR;

        // ---- P4: no ds_reads || stage A1(t+2); counted vmcnt ----
        if (t + 2 < nk) {
            stgA(cur, 1, t + 2);
            asm volatile("s_waitcnt vmcnt(4)" ::: "memory");   // tile t+1 resident; A(t+2) in flight
        } else {
            asm volatile("s_waitcnt vmcnt(0)" ::: "memory");   // drain (B(t+1) or final)
        }
        BAR;
        __builtin_amdgcn_s_setprio(1);
        MFMA_Q(af47, 4, bf23, 2);
        __builtin_amdgcn_s_setprio(0);
        BAR;
    }

    C += (long)b * sC;

    #pragma unroll
    for (int nf = 0; nf < 4; ++nf) {
        const int col = n0 + wq * 64 + nf * 16 + l16;
        float fr = 0.f;
        if (EPI == EPI_SINUS)
            fr = __expf((float)(-(col & ~1)) * (9.210340371976184f / 1024.f)); // exp(-(2i)ln(1e4)/d)
        #pragma unroll
        for (int mf = 0; mf < 8; ++mf) {
            #pragma unroll
            for (int r = 0; r < 4; ++r) {
                const int row = m0 + hw * 128 + mf * 16 + quad * 4 + r; // C/D: row=quad*4+reg, col=l16
                float v = acc[mf][nf][r];
                if (EPI == EPI_SINUS) {
                    float ang = (float)row * fr;
                    // __sinf/__cosf: inline v_sin/v_cos, no libcall (libcall ABI clamped VGPRs)
                    v += (col & 1) ? __cosf(ang) : __sinf(ang);
                }
                if (EPI == EPI_BIAS) v += bias[row];
                if (row < mLimit)
                    C[(long)row * ldc + col] = (CT)v;
            }
        }
    }

    if (EPI == EPI_ATTN) {
        // per-column (max, sum-exp) over this block's 256 rows (rows >= mLimit masked)
        float nmx[4], nsm[4];
        #pragma unroll
        for (int nf = 0; nf < 4; ++nf) {
            float mx = -1e30f;
            #pragma unroll
            for (int mf = 0; mf < 8; ++mf)
                #pragma unroll
                for (int r = 0; r < 4; ++r) {
                    const int row = m0 + hw * 128 + mf * 16 + quad * 4 + r;
                    float v = (row < mLimit) ? acc[mf][nf][r] : -1e30f;
                    mx = fmaxf(mx, v);
                }
            float sm = 0.f;
            #pragma unroll
            for (int mf = 0; mf < 8; ++mf)
                #pragma unroll
                for (int r = 0; r < 4; ++r) {
                    const int row = m0 + hw * 128 + mf * 16 + quad * 4 + r;
                    float v = (row < mLimit) ? acc[mf][nf][r] : -1e30f;
                    sm += __expf(v - mx);   // masked v underflows to 0
                }
            // merge across quads (same col: lanes l16, l16+16, l16+32, l16+48)
            float omx = __shfl_xor(mx, 16), osm = __shfl_xor(sm, 16);
            onl_merge(mx, sm, omx, osm);
            omx = __shfl_xor(mx, 32); osm = __shfl_xor(sm, 32);
            onl_merge(mx, sm, omx, osm);
            nmx[nf] = mx; nsm[nf] = sm;
        }
        // lane keeps nf == quad  ->  col-in-wave == lane  (static select, no scratch)
        float smx = quad == 0 ? nmx[0] : quad == 1 ? nmx[1] : quad == 2 ? nmx[2] : nmx[3];
        float ssm = quad == 0 ? nsm[0] : quad == 1 ? nsm[1] : quad == 2 ? nsm[2] : nsm[3];
        float2* red = (float2*)smem;     // staging LDS dead (final vmcnt(0)+BAR in loop)
        red[wave * 64 + lane] = make_float2(smx, ssm);
        __syncthreads();
        if (wave < 4) {                  // merge hw=0 with hw=1 (waves wq and wq+4)
            float2 x = red[wave * 64 + lane];
            float2 y = red[(wave + 4) * 64 + lane];
            onl_merge(x.x, x.y, y.x, y.y);
            const int col = n0 + wq * 64 + lane;
            const int mt  = m0 >> 8;
            pmx [((long)b * 4 + mt) * 1024 + col] = x.x;
            psum[((long)b * 4 + mt) * 1024 + col] = x.y;
        }
    }
}

// f32 -> bf16 flat convert (n % 4 == 0)
__launch_bounds__(256)
__global__ void cvt_f32_bf16(const float* __restrict__ in, bf16* __restrict__ out, int n)
{
    int i = (blockIdx.x * 256 + threadIdx.x) * 4;
    if (i < n) {
        float4 v = *(const float4*)(in + i);
        out[i]     = (bf16)v.x;
        out[i + 1] = (bf16)v.y;
        out[i + 2] = (bf16)v.z;
        out[i + 3] = (bf16)v.w;
    }
}

// batched transpose + f32->bf16: in (rows x cols) f32 -> out (cols x rows) bf16
__launch_bounds__(256)
__global__ void transpose_f32_bf16(const float* __restrict__ in, bf16* __restrict__ out,
                                   int rows, int cols)
{
    __shared__ float tile[32][33];
    const long bs = (long)rows * cols;
    in  += (long)blockIdx.z * bs;
    out += (long)blockIdx.z * bs;
    const int c0 = blockIdx.x * 32, r0 = blockIdx.y * 32;
    const int tx = threadIdx.x, ty = threadIdx.y;
    #pragma unroll
    for (int i = ty; i < 32; i += 8)
        tile[i][tx] = in[(long)(r0 + i) * cols + c0 + tx];
    __syncthreads();
    #pragma unroll
    for (int i = ty; i < 32; i += 8)
        out[(long)(c0 + i) * rows + r0 + tx] = (bf16)tile[tx][i];
}

// batched bf16 transpose: in (rows x cols) -> out (cols x rows)
__launch_bounds__(256)
__global__ void transpose_bf16(const bf16* __restrict__ in, bf16* __restrict__ out,
                               int rows, int cols)
{
    __shared__ bf16 tile[32][33];
    const long bs = (long)rows * cols;
    in  += (long)blockIdx.z * bs;
    out += (long)blockIdx.z * bs;
    const int c0 = blockIdx.x * 32, r0 = blockIdx.y * 32;
    const int tx = threadIdx.x, ty = threadIdx.y;
    #pragma unroll
    for (int i = ty; i < 32; i += 8)
        tile[i][tx] = in[(long)(r0 + i) * cols + c0 + tx];
    __syncthreads();
    #pragma unroll
    for (int i = ty; i < 32; i += 8)
        out[(long)(c0 + i) * rows + r0 + tx] = tile[tx][i];
}

// ---------- softmax normalize + transpose ----------
// Merges the 4 per-mtile partials, normalizes attn columns, writes softT[t][m] directly
// (64x64 LDS tile transpose, coalesced both sides). Row m==1023 -> 0 (K-pad for A1 gemm).
__launch_bounds__(256)
__global__ void softmax_norm_T(const float* __restrict__ attn,
                               const float* __restrict__ pmx,
                               const float* __restrict__ psum,
                               bf16* __restrict__ softT)
{
    __shared__ bf16 tile[64][66];   // [t-idx][m-idx], 66 pad -> conflict-free both phases
    const int b  = blockIdx.z;
    const int mt = blockIdx.x;      // attn row tile (0..15), rows m0..m0+63
    const int ct = blockIdx.y;      // attn col tile (0..15), cols c0..c0+63 (= softT rows)
    const int tx = threadIdx.x & 63;
    const int ty = threadIdx.x >> 6;
    const int col = ct * 64 + tx;

    float MX = -1e30f, SM = 0.f;
    #pragma unroll
    for (int p = 0; p < 4; ++p) {
        float omx = pmx [((long)b * 4 + p) * 1024 + col];
        float osm = psum[((long)b * 4 + p) * 1024 + col];
        onl_merge(MX, SM, omx, osm);
    }
    const float INV = 1.f / SM;

    const float* a = attn + (long)b * (1023l * 1024);
    const int m0 = mt * 64;
    #pragma unroll
    for (int i = ty; i < 64; i += 4) {
        const int m = m0 + i;
        float p = 0.f;
        if (m < 1023) p = __expf(a[(long)m * 1024 + col] - MX) * INV;
        tile[tx][i] = (bf16)p;
    }
    __syncthreads();
    bf16* o = softT + (long)b * (1024l * 1024) + (long)(ct * 64) * 1024 + m0;
    #pragma unroll
    for (int j = ty; j < 64; j += 4)
        o[(long)j * 1024 + tx] = tile[j][tx];
}

extern "C" void kernel_launch(void* const* d_in, const int* in_sizes, int n_in,
                              void* d_out, int out_size, void* d_ws, size_t ws_size,
                              hipStream_t stream)
{
    const float* xs    = (const float*)d_in[0];  // (32,512,1024) f32
    const float* W_emb = (const float*)d_in[1];  // (1024,512)
    const float* W_KQ  = (const float*)d_in[2];  // (1024,1024)
    const float* W_PV  = (const float*)d_in[3];  // (1024,1024)
    const float* W_un  = (const float*)d_in[4];  // (512,1024)
    const float* b_un  = (const float*)d_in[5];  // (512,)

    float* out  = (float*)d_out;                   // (32,512,1024) f32
    float* attn = out + (size_t)32 * 512 * 1024;   // (32,1023,1024) f32

    const long MB = 1024l * 1024;

    // workspace layout (bytes), bf16 buffers
    char* ws = (char*)d_ws;
    const size_t oXsT  = 0;                        // 32*1024*512*2 = 33.5 MB
    const size_t oET   = oXsT + (size_t)33554432;  // 64 MB each below
    const size_t oEn   = oET  + (size_t)67108864;
    const size_t oQT   = oEn  + (size_t)67108864;
    const size_t oR    = oQT  + (size_t)67108864;
    const size_t oWe   = oR   + (size_t)67108864;  // weights bf16: 1+2+2+1 MB
    const size_t oWkq  = oWe  + (size_t)1048576;
    const size_t oWpv  = oWkq + (size_t)2097152;
    const size_t oWun  = oWpv + (size_t)2097152;
    const size_t need  = oWun + (size_t)1048576;
    if (ws_size < need) { fprintf(stderr, "ws too small: %zu < %zu\n", ws_size, need); return; }

    bf16* xsT   = (bf16*)(ws + oXsT);
    bf16* ET    = (bf16*)(ws + oET);
    bf16* En    = (bf16*)(ws + oEn);
    bf16* QT    = (bf16*)(ws + oQT);
    bf16* We    = (bf16*)(ws + oWe);
    bf16* Wkq   = (bf16*)(ws + oWkq);
    bf16* Wpv   = (bf16*)(ws + oWpv);
    bf16* Wun   = (bf16*)(ws + oWun);
    bf16* softT = QT;                 // reuse: QT dead after attn gemm
    bf16* A1T   = (bf16*)(ws + oR);
    bf16* fT    = ET;                 // reuse: ET dead after attn gemm

    // softmax partials parked in R's space (A1T written only after softmax_norm_T consumed them)
    float* pmx  = (float*)(ws + oR);               // 32*4*1024 f32 = 512 KB
    float* psum = pmx + (size_t)32 * 4 * 1024;     // +512 KB

    const dim3 tb(32, 8);
    const int BIG = 1 << 30;

    // weight converts f32 -> bf16
    cvt_f32_bf16<<<512, 256, 0, stream>>>(W_emb, We, 524288);
    cvt_f32_bf16<<<1024, 256, 0, stream>>>(W_KQ, Wkq, 1048576);
    cvt_f32_bf16<<<1024, 256, 0, stream>>>(W_PV, Wpv, 1048576);
    cvt_f32_bf16<<<512, 256, 0, stream>>>(W_un, Wun, 524288);
    // xs (512x1024 f32) -> xsT (1024x512 bf16), per batch
    transpose_f32_bf16<<<dim3(32, 16, 32), tb, 0, stream>>>(xs, xsT, 512, 1024);
    // E^T[t][d] = sum_n xsT[t][n] * We[d][n] + sinusoid(t,d)
    gemm8<EPI_SINUS, bf16><<<dim3(512), 512, 0, stream>>>(
        xsT, 512l * 1024, 512, We, 0, 512, ET, MB, 1024, 512, BIG, nullptr, nullptr, nullptr, 4, 4);
    // E^T -> E (natural [e][m])
    transpose_bf16<<<dim3(32, 32, 32), tb, 0, stream>>>(ET, En, 1024, 1024);
    // Q^T[t][d] = sum_e E^T[t][e] * Wkq[d][e]
    gemm8<EPI_NONE, bf16><<<dim3(512), 512, 0, stream>>>(
        ET, MB, 1024, Wkq, 0, 1024, QT, MB, 1024, 1024, BIG, nullptr, nullptr, nullptr, 4, 4);
    // attn[m][t] = sum_e E^T[m][e] * Q^T[t][e], rows m<1023, f32 -> d_out; + column partials
    gemm8<EPI_ATTN, float><<<dim3(512), 512, 0, stream>>>(
        ET, MB, 1024, QT, MB, 1024, attn, 1023l * 1024, 1024, 1024, 1023, nullptr, pmx, psum, 4, 4);
    // merge partials + normalize + transpose-write softT [t][m] (row 1023 of soft -> 0)
    softmax_norm_T<<<dim3(16, 16, 32), 256, 0, stream>>>(attn, pmx, psum, softT);
    // A1^T[t][e] = sum_m softT[t][m] * E[e][m]
    gemm8<EPI_NONE, bf16><<<dim3(512), 512, 0, stream>>>(
        softT, MB, 1024, En, MB, 1024, A1T, MB, 1024, 1024, BIG, nullptr, nullptr, nullptr, 4, 4);
    // f_attn^T[t][d] = sum_e A1^T[t][e] * Wpv[d][e]
    gemm8<EPI_NONE, bf16><<<dim3(512), 512, 0, stream>>>(
        A1T, MB, 1024, Wpv, 0, 1024, fT, MB, 1024, 1024, BIG, nullptr, nullptr, nullptr, 4, 4);
    // out[o][t] = sum_d Wun[o][d] * f_attn^T[t][d] + b_un[o], f32 -> d_out
    gemm8<EPI_BIAS, float><<<dim3(256), 512, 0, stream>>>(
        Wun, 0, 1024, fT, MB, 1024, out, 512l * 1024, 1024, 1024, BIG, b_un, nullptr, nullptr, 2, 4);
}

// Round 4
// 744.504 us; speedup vs baseline: 1.9593x; 1.0760x over previous
//
#include <hip/hip_runtime.h>
#include <hip/hip_bf16.h>
#include <cstdio>

typedef __bf16 bf16;
typedef __bf16 bf16x4 __attribute__((ext_vector_type(4)));
typedef __bf16 bf16x8 __attribute__((ext_vector_type(8)));
typedef float  f32x4  __attribute__((ext_vector_type(4)));

#define AS1 __attribute__((address_space(1)))
#define AS3 __attribute__((address_space(3)))

__device__ __forceinline__ void async16(void* lds, const void* g) {
    __builtin_amdgcn_global_load_lds((AS1 unsigned int*)g, (AS3 unsigned int*)lds, 16, 0, 0);
}

enum { EPI_NONE = 0, EPI_SINUS = 1, EPI_BIAS = 2, EPI_ATTN = 3 };

#define FENCE asm volatile("" ::: "memory")
#define BAR   do { FENCE; __builtin_amdgcn_s_barrier(); FENCE; } while (0)
// NOTE: no sched_barrier(0) here. Rule #18 applies to inline-asm ds_reads only; ours are
// compiler-tracked loads. A sched_barrier(0) before every MFMA cluster pins the schedule
// (m141: 510 TF regression). The bare lgkmcnt(0) keeps the phase discipline of the template.
#define LGKM0 asm volatile("s_waitcnt lgkmcnt(0)" ::: "memory")
#define RD8(p) (*(const bf16x8*)(const void*)(p))

// 16 MFMA: quadrant rows (MB..MB+3) x cols (NB..NB+1), K=64 (2 ksubs)
#define MFMA_Q(AF, MB, BF, NB)                                                 \
    _Pragma("unroll") for (int mf = 0; mf < 4; ++mf)                           \
    _Pragma("unroll") for (int nf = 0; nf < 2; ++nf)                           \
    _Pragma("unroll") for (int s = 0; s < 2; ++s)                              \
        acc[(MB) + mf][(NB) + nf] = __builtin_amdgcn_mfma_f32_16x16x32_bf16(   \
            AF[mf][s], BF[nf][s], acc[(MB) + mf][(NB) + nf], 0, 0, 0);

__device__ __forceinline__ void onl_merge(float& mx, float& sm, float omx, float osm) {
    float nm = fmaxf(mx, omx);
    sm = sm * __expf(mx - nm) + osm * __expf(omx - nm);
    mx = nm;
}

// ---------------- 256x256 8-phase NT GEMM (m201-style template) ----------------
// C[m][n] = sum_k A[m][k]*B[n][k], bf16 in, CT out. BM=BN=256, BK=64, 512 thr (8 waves 2Mx4N).
// LDS 128KB: A[2buf][2half][128][64] + B same. XOR-swizzle byte^=((row&7)<<4) on BOTH the
// pre-swizzled global_load_lds source and the ds_read address (involution, conflict-free).
// Quadrant order (0,0)->(0,2)->(4,0)->(4,2) keeps fragment liveness low (~220 VGPR peak).
// Stage schedule: P1:B0(t+1) P2:B1(t+1) P3:A0(t+2) P4:A1(t+2); single counted vmcnt(4) at P4.
// EPI_ATTN: epilogue also reduces per-column (max, sum-exp) over the block's 256 rows.
template <int EPI, typename CT>
__launch_bounds__(512, 2)
__global__ void gemm8(const bf16* __restrict__ A, long sA, int lda,
                      const bf16* __restrict__ B, long sB, int ldb,
                      CT* __restrict__ C, long sC, int ldc,
                      int K, int mLimit, const float* __restrict__ bias,
                      float* __restrict__ pmx, float* __restrict__ psum,
                      int tilesM, int tilesN)
{
    __shared__ __align__(16) char smem[131072];
    char* ldsA = smem;
    char* ldsB = smem + 65536;

    const int tid  = threadIdx.x;
    const int wave = tid >> 6;
    const int lane = tid & 63;
    const int quad = lane >> 4;
    const int l16  = lane & 15;
    const int hw   = wave >> 2;        // wave's A half (M strip)
    const int wq   = wave & 3;         // wave's N strip (64 cols)
    const int hbB  = wq >> 1;          // wave's B half
    const int rrB  = (wq & 1) * 64;    // row base within B half

    // T1: bijective XCD-chunked swizzle
    const int nwg = gridDim.x;
    const int qq = nwg >> 3, rr = nwg & 7;
    const int xcd = blockIdx.x & 7, idx = blockIdx.x >> 3;
    const int wgid = (xcd < rr ? xcd * (qq + 1) : rr * (qq + 1) + (xcd - rr) * qq) + idx;

    const int tpb = tilesM * tilesN;
    const int b   = wgid / tpb;
    const int rem = wgid - b * tpb;
    const int m0  = (rem / tilesN) * 256;
    const int n0  = (rem % tilesN) * 256;

    A += (long)b * sA;
    B += (long)b * sB;

    // staging: dest (linear) od = wave*1024 + lane*16 (+ j*8192); source pre-swizzled so that
    // LDS[od] = G[od ^ ((destrow&7)<<4)]
    const int odt  = wave * 1024 + lane * 16;
    const int ol   = odt ^ (((odt >> 7) & 7) << 4);
    const int srow = ol >> 7;            // 0..63
    const int scol = (ol & 127) >> 1;    // element col, multiple of 8
    const bf16* pA = A + (long)(m0 + srow) * lda + scol;
    const bf16* pB = B + (long)(n0 + srow) * ldb + scol;

    // ds_read lane offsets: logical (row*128 + s*64 + quad*16) ^ ((row&7)<<4); row&7 == l16&7
    const int xr = (l16 & 7) << 4;
    const int lane2_0 = ((l16 * 128) + (quad * 16)) ^ xr;
    const int lane2_1 = ((l16 * 128) + 64 + (quad * 16)) ^ xr;

    auto stgA = [&](int bb, int h, int kt) {
        char* l = ldsA + bb * 32768 + h * 16384 + wave * 1024;
        const bf16* g = pA + (long)(h * 128) * lda + kt * 64;
        async16(l, g);
        async16(l + 8192, g + (long)64 * lda);
    };
    auto stgB = [&](int bb, int h, int kt) {
        char* l = ldsB + bb * 32768 + h * 16384 + wave * 1024;
        const bf16* g = pB + (long)(h * 128) * ldb + kt * 64;
        async16(l, g);
        async16(l + 8192, g + (long)64 * ldb);
    };

    const int nk = K >> 6;

    // prologue: tile0 all 4 halves + A halves of tile1; vmcnt(4) leaves A(1) in flight
    stgA(0, 0, 0); stgA(0, 1, 0);
    stgB(0, 0, 0); stgB(0, 1, 0);
    stgA(1, 0, 1); stgA(1, 1, 1);
    asm volatile("s_waitcnt vmcnt(4)" ::: "memory");
    BAR;

    f32x4 acc[8][4] = {};

    for (int t = 0; t < nk; ++t) {
        const int cur = t & 1;
        const char* aH = ldsA + cur * 32768 + hw * 16384;
        const char* bH = ldsB + cur * 32768 + hbB * 16384 + rrB * 128;

        bf16x8 af03[4][2], af47[4][2], bf01[2][2], bf23[2][2];

        // ---- P1: af03 (8) + bf01 (4) || stage B0(t+1) ----
        #pragma unroll
        for (int mf = 0; mf < 4; ++mf) {
            af03[mf][0] = RD8(aH + mf * 2048 + lane2_0);
            af03[mf][1] = RD8(aH + mf * 2048 + lane2_1);
        }
        #pragma unroll
        for (int nf = 0; nf < 2; ++nf) {
            bf01[nf][0] = RD8(bH + nf * 2048 + lane2_0);
            bf01[nf][1] = RD8(bH + nf * 2048 + lane2_1);
        }
        if (t + 1 < nk) stgB(cur ^ 1, 0, t + 1);
        BAR;
        LGKM0;
        __builtin_amdgcn_s_setprio(1);
        MFMA_Q(af03, 0, bf01, 0);
        __builtin_amdgcn_s_setprio(0);
        BAR;

        // ---- P2: bf23 (4) || stage B1(t+1) ----
        #pragma unroll
        for (int nf = 0; nf < 2; ++nf) {
            bf23[nf][0] = RD8(bH + (nf + 2) * 2048 + lane2_0);
            bf23[nf][1] = RD8(bH + (nf + 2) * 2048 + lane2_1);
        }
        if (t + 1 < nk) stgB(cur ^ 1, 1, t + 1);
        BAR;
        LGKM0;
        __builtin_amdgcn_s_setprio(1);
        MFMA_Q(af03, 0, bf23, 2);          // af03 dead after this
        __builtin_amdgcn_s_setprio(0);
        BAR;

        // ---- P3: af47 (8) || stage A0(t+2) (A region of cur is dead) ----
        #pragma unroll
        for (int mf = 0; mf < 4; ++mf) {
            af47[mf][0] = RD8(aH + (mf + 4) * 2048 + lane2_0);
            af47[mf][1] = RD8(aH + (mf + 4) * 2048 + lane2_1);
        }
        if (t + 2 < nk) stgA(cur, 0, t + 2);
        BAR;
        LGKM0;
        __builtin_amdgcn_s_setprio(1);
        MFMA_Q(af47, 4, bf01, 0);          // bf01 dead after this
        __builtin_amdgcn_s_setprio(0);
        BAR;

        // ---- P4: no ds_reads || stage A1(t+2); counted vmcnt ----
        if (t + 2 < nk) {
            stgA(cur, 1, t + 2);
            asm volatile("s_waitcnt vmcnt(4)" ::: "memory");   // tile t+1 resident; A(t+2) in flight
        } else {
            asm volatile("s_waitcnt vmcnt(0)" ::: "memory");   // drain
        }
        BAR;
        __builtin_amdgcn_s_setprio(1);
        MFMA_Q(af47, 4, bf23, 2);
        __builtin_amdgcn_s_setprio(0);
        BAR;
    }

    C += (long)b * sC;

    #pragma unroll
    for (int nf = 0; nf < 4; ++nf) {
        const int col = n0 + wq * 64 + nf * 16 + l16;
        float fr = 0.f;
        if (EPI == EPI_SINUS)
            fr = __expf((float)(-(col & ~1)) * (9.210340371976184f / 1024.f)); // exp(-(2i)ln(1e4)/d)
        #pragma unroll
        for (int mf = 0; mf < 8; ++mf) {
            #pragma unroll
            for (int r = 0; r < 4; ++r) {
                const int row = m0 + hw * 128 + mf * 16 + quad * 4 + r; // C/D: row=quad*4+reg, col=l16
                float v = acc[mf][nf][r];
                if (EPI == EPI_SINUS) {
                    float ang = (float)row * fr;
                    // __sinf/__cosf: inline v_sin/v_cos, no libcall (libcall ABI clamped VGPRs)
                    v += (col & 1) ? __cosf(ang) : __sinf(ang);
                }
                if (EPI == EPI_BIAS) v += bias[row];
                if (row < mLimit)
                    C[(long)row * ldc + col] = (CT)v;
            }
        }
    }

    if (EPI == EPI_ATTN) {
        // per-column (max, sum-exp) over this block's 256 rows (rows >= mLimit masked)
        float nmx[4], nsm[4];
        #pragma unroll
        for (int nf = 0; nf < 4; ++nf) {
            float mx = -1e30f;
            #pragma unroll
            for (int mf = 0; mf < 8; ++mf)
                #pragma unroll
                for (int r = 0; r < 4; ++r) {
                    const int row = m0 + hw * 128 + mf * 16 + quad * 4 + r;
                    float v = (row < mLimit) ? acc[mf][nf][r] : -1e30f;
                    mx = fmaxf(mx, v);
                }
            float sm = 0.f;
            #pragma unroll
            for (int mf = 0; mf < 8; ++mf)
                #pragma unroll
                for (int r = 0; r < 4; ++r) {
                    const int row = m0 + hw * 128 + mf * 16 + quad * 4 + r;
                    float v = (row < mLimit) ? acc[mf][nf][r] : -1e30f;
                    sm += __expf(v - mx);   // masked v underflows to 0
                }
            float omx = __shfl_xor(mx, 16), osm = __shfl_xor(sm, 16);
            onl_merge(mx, sm, omx, osm);
            omx = __shfl_xor(mx, 32); osm = __shfl_xor(sm, 32);
            onl_merge(mx, sm, omx, osm);
            nmx[nf] = mx; nsm[nf] = sm;
        }
        float smx = quad == 0 ? nmx[0] : quad == 1 ? nmx[1] : quad == 2 ? nmx[2] : nmx[3];
        float ssm = quad == 0 ? nsm[0] : quad == 1 ? nsm[1] : quad == 2 ? nsm[2] : nsm[3];
        float2* red = (float2*)smem;     // staging LDS dead (final vmcnt(0)+BAR in loop)
        red[wave * 64 + lane] = make_float2(smx, ssm);
        __syncthreads();
        if (wave < 4) {
            float2 x = red[wave * 64 + lane];
            float2 y = red[(wave + 4) * 64 + lane];
            onl_merge(x.x, x.y, y.x, y.y);
            const int col = n0 + wq * 64 + lane;
            const int mt  = m0 >> 8;
            pmx [((long)b * 4 + mt) * 1024 + col] = x.x;
            psum[((long)b * 4 + mt) * 1024 + col] = x.y;
        }
    }
}

// ---------------- small 128x128 2-phase NT GEMM (for tiny weight-fold gemms) ----------------
constexpr int BM = 128, BN = 128, BK = 32;
template <int EPI, typename CT>
__launch_bounds__(256)
__global__ void gemm_nt(const bf16* __restrict__ A, long sA, int lda,
                        const bf16* __restrict__ B, long sB, int ldb,
                        CT* __restrict__ C, long sC, int ldc,
                        int K, int mLimit,
                        const float* __restrict__ bias)
{
    __shared__ __align__(16) bf16 As[BM * BK];
    __shared__ __align__(16) bf16 Bs[BN * BK];

    const int tid  = threadIdx.x;
    const int wave = tid >> 6;
    const int lane = tid & 63;
    const int quad = lane >> 4;
    const int l16  = lane & 15;
    const int b    = blockIdx.z;
    const int m0   = blockIdx.y * BM;
    const int n0   = blockIdx.x * BN;

    A += (long)b * sA;
    B += (long)b * sB;

    const int srow = lane >> 2;
    const int scol = (lane & 3) * 8;
    const bf16* gA = A + (long)(m0 + wave * 32 + srow) * lda + scol;
    const bf16* gB = B + (long)(n0 + wave * 32 + srow) * ldb + scol;
    char* lA = (char*)As + wave * 2048;
    char* lB = (char*)Bs + wave * 2048;

    const int wm = (wave >> 1) * 64;
    const int wn = (wave & 1) * 64;

    f32x4 acc[4][4] = {};

    for (int k0 = 0; k0 < K; k0 += BK) {
        __syncthreads();
        async16(lA,        gA);
        async16(lA + 1024, gA + (long)16 * lda);
        async16(lB,        gB);
        async16(lB + 1024, gB + (long)16 * ldb);
        gA += BK; gB += BK;
        __syncthreads();

        bf16x8 af[4], bfr[4];
        #pragma unroll
        for (int i = 0; i < 4; i++) {
            af[i]  = *(const bf16x8*)(As + (wm + i * 16 + l16) * BK + quad * 8);
            bfr[i] = *(const bf16x8*)(Bs + (wn + i * 16 + l16) * BK + quad * 8);
        }
        #pragma unroll
        for (int mi = 0; mi < 4; mi++)
            #pragma unroll
            for (int ni = 0; ni < 4; ni++)
                acc[mi][ni] = __builtin_amdgcn_mfma_f32_16x16x32_bf16(
                    af[mi], bfr[ni], acc[mi][ni], 0, 0, 0);
    }

    C += (long)b * sC;

    #pragma unroll
    for (int ni = 0; ni < 4; ni++) {
        const int col = n0 + wn + ni * 16 + l16;
        #pragma unroll
        for (int mi = 0; mi < 4; mi++) {
            #pragma unroll
            for (int r = 0; r < 4; r++) {
                const int row = m0 + wm + mi * 16 + quad * 4 + r;
                float v = acc[mi][ni][r];
                if (EPI == EPI_BIAS) v += bias[row];
                if (row < mLimit)
                    C[(long)row * ldc + col] = (CT)v;
            }
        }
    }
}

// f32 -> bf16 flat convert (n % 4 == 0)
__launch_bounds__(256)
__global__ void cvt_f32_bf16(const float* __restrict__ in, bf16* __restrict__ out, int n)
{
    int i = (blockIdx.x * 256 + threadIdx.x) * 4;
    if (i < n) {
        float4 v = *(const float4*)(in + i);
        out[i]     = (bf16)v.x;
        out[i + 1] = (bf16)v.y;
        out[i + 2] = (bf16)v.z;
        out[i + 3] = (bf16)v.w;
    }
}

// batched transpose + f32->bf16: in (rows x cols) f32 -> out (cols x rows) bf16
__launch_bounds__(256)
__global__ void transpose_f32_bf16(const float* __restrict__ in, bf16* __restrict__ out,
                                   int rows, int cols)
{
    __shared__ float tile[32][33];
    const long bs = (long)rows * cols;
    in  += (long)blockIdx.z * bs;
    out += (long)blockIdx.z * bs;
    const int c0 = blockIdx.x * 32, r0 = blockIdx.y * 32;
    const int tx = threadIdx.x, ty = threadIdx.y;
    #pragma unroll
    for (int i = ty; i < 32; i += 8)
        tile[i][tx] = in[(long)(r0 + i) * cols + c0 + tx];
    __syncthreads();
    #pragma unroll
    for (int i = ty; i < 32; i += 8)
        out[(long)(c0 + i) * rows + r0 + tx] = (bf16)tile[tx][i];
}

// batched bf16 transpose: in (rows x cols) -> out (cols x rows)
__launch_bounds__(256)
__global__ void transpose_bf16(const bf16* __restrict__ in, bf16* __restrict__ out,
                               int rows, int cols)
{
    __shared__ bf16 tile[32][33];
    const long bs = (long)rows * cols;
    in  += (long)blockIdx.z * bs;
    out += (long)blockIdx.z * bs;
    const int c0 = blockIdx.x * 32, r0 = blockIdx.y * 32;
    const int tx = threadIdx.x, ty = threadIdx.y;
    #pragma unroll
    for (int i = ty; i < 32; i += 8)
        tile[i][tx] = in[(long)(r0 + i) * cols + c0 + tx];
    __syncthreads();
    #pragma unroll
    for (int i = ty; i < 32; i += 8)
        out[(long)(c0 + i) * rows + r0 + tx] = tile[tx][i];
}

// ---------- softmax normalize + transpose ----------
// Merges the 4 per-mtile partials, normalizes attn columns, writes softT[t][m] directly.
__launch_bounds__(256)
__global__ void softmax_norm_T(const float* __restrict__ attn,
                               const float* __restrict__ pmx,
                               const float* __restrict__ psum,
                               bf16* __restrict__ softT)
{
    __shared__ bf16 tile[64][66];
    const int b  = blockIdx.z;
    const int mt = blockIdx.x;
    const int ct = blockIdx.y;
    const int tx = threadIdx.x & 63;
    const int ty = threadIdx.x >> 6;
    const int col = ct * 64 + tx;

    float MX = -1e30f, SM = 0.f;
    #pragma unroll
    for (int p = 0; p < 4; ++p) {
        float omx = pmx [((long)b * 4 + p) * 1024 + col];
        float osm = psum[((long)b * 4 + p) * 1024 + col];
        onl_merge(MX, SM, omx, osm);
    }
    const float INV = 1.f / SM;

    const float* a = attn + (long)b * (1023l * 1024);
    const int m0 = mt * 64;
    #pragma unroll
    for (int i = ty; i < 64; i += 4) {
        const int m = m0 + i;
        float p = 0.f;
        if (m < 1023) p = __expf(a[(long)m * 1024 + col] - MX) * INV;
        tile[tx][i] = (bf16)p;
    }
    __syncthreads();
    bf16* o = softT + (long)b * (1024l * 1024) + (long)(ct * 64) * 1024 + m0;
    #pragma unroll
    for (int j = ty; j < 64; j += 4)
        o[(long)j * 1024 + tx] = tile[j][tx];
}

extern "C" void kernel_launch(void* const* d_in, const int* in_sizes, int n_in,
                              void* d_out, int out_size, void* d_ws, size_t ws_size,
                              hipStream_t stream)
{
    const float* xs    = (const float*)d_in[0];  // (32,512,1024) f32
    const float* W_emb = (const float*)d_in[1];  // (1024,512)
    const float* W_KQ  = (const float*)d_in[2];  // (1024,1024)
    const float* W_PV  = (const float*)d_in[3];  // (1024,1024)
    const float* W_un  = (const float*)d_in[4];  // (512,1024)
    const float* b_un  = (const float*)d_in[5];  // (512,)

    float* out  = (float*)d_out;                   // (32,512,1024) f32
    float* attn = out + (size_t)32 * 512 * 1024;   // (32,1023,1024) f32

    const long MB = 1024l * 1024;

    // workspace layout (bytes), bf16 buffers
    char* ws = (char*)d_ws;
    const size_t oXsT  = 0;                        // 32*1024*512*2 = 33.5 MB
    const size_t oET   = oXsT + (size_t)33554432;  // 64 MB each below
    const size_t oEn   = oET  + (size_t)67108864;
    const size_t oQT   = oEn  + (size_t)67108864;
    const size_t oR    = oQT  + (size_t)67108864;
    const size_t oWe   = oR   + (size_t)67108864;  // weights bf16
    const size_t oWkq  = oWe  + (size_t)1048576;
    const size_t oWpvT = oWkq + (size_t)2097152;   // W_PV^T bf16 (2 MB)
    const size_t oWun  = oWpvT + (size_t)2097152;
    const size_t oWc   = oWun + (size_t)1048576;   // Wc = Wun@Wpv bf16 (512x1024, 1 MB)
    const size_t need  = oWc  + (size_t)1048576;
    if (ws_size < need) { fprintf(stderr, "ws too small: %zu < %zu\n", ws_size, need); return; }

    bf16* xsT   = (bf16*)(ws + oXsT);
    bf16* ET    = (bf16*)(ws + oET);
    bf16* En    = (bf16*)(ws + oEn);
    bf16* QT    = (bf16*)(ws + oQT);
    bf16* We    = (bf16*)(ws + oWe);
    bf16* Wkq   = (bf16*)(ws + oWkq);
    bf16* WpvT  = (bf16*)(ws + oWpvT);
    bf16* Wun   = (bf16*)(ws + oWun);
    bf16* Wc    = (bf16*)(ws + oWc);
    bf16* softT = QT;                 // reuse: QT dead after attn gemm
    bf16* A1T   = (bf16*)(ws + oR);

    // softmax partials parked in R's space (A1T written only after softmax_norm_T consumed them)
    float* pmx  = (float*)(ws + oR);               // 32*4*1024 f32 = 512 KB
    float* psum = pmx + (size_t)32 * 4 * 1024;     // +512 KB

    const dim3 tb(32, 8);
    const int BIG = 1 << 30;

    // weight converts f32 -> bf16
    cvt_f32_bf16<<<512, 256, 0, stream>>>(W_emb, We, 524288);
    cvt_f32_bf16<<<1024, 256, 0, stream>>>(W_KQ, Wkq, 1048576);
    cvt_f32_bf16<<<512, 256, 0, stream>>>(W_un, Wun, 524288);
    // W_PV (1024x1024 f32) -> WpvT bf16 [e][d]
    transpose_f32_bf16<<<dim3(32, 32, 1), tb, 0, stream>>>(W_PV, WpvT, 1024, 1024);
    // Wc[o][e] = sum_d Wun[o][d] * WpvT[e][d]  (batch-independent fold of W_un @ W_PV)
    gemm_nt<EPI_NONE, bf16><<<dim3(8, 4, 1), 256, 0, stream>>>(
        Wun, 0, 1024, WpvT, 0, 1024, Wc, 0, 1024, 1024, BIG, nullptr);
    // xs (512x1024 f32) -> xsT (1024x512 bf16), per batch
    transpose_f32_bf16<<<dim3(32, 16, 32), tb, 0, stream>>>(xs, xsT, 512, 1024);
    // E^T[t][d] = sum_n xsT[t][n] * We[d][n] + sinusoid(t,d)
    gemm8<EPI_SINUS, bf16><<<dim3(512), 512, 0, stream>>>(
        xsT, 512l * 1024, 512, We, 0, 512, ET, MB, 1024, 512, BIG, nullptr, nullptr, nullptr, 4, 4);
    // E^T -> E (natural [e][m])
    transpose_bf16<<<dim3(32, 32, 32), tb, 0, stream>>>(ET, En, 1024, 1024);
    // Q^T[t][d] = sum_e E^T[t][e] * Wkq[d][e]
    gemm8<EPI_NONE, bf16><<<dim3(512), 512, 0, stream>>>(
        ET, MB, 1024, Wkq, 0, 1024, QT, MB, 1024, 1024, BIG, nullptr, nullptr, nullptr, 4, 4);
    // attn[m][t] = sum_e E^T[m][e] * Q^T[t][e], rows m<1023, f32 -> d_out; + column partials
    gemm8<EPI_ATTN, float><<<dim3(512), 512, 0, stream>>>(
        ET, MB, 1024, QT, MB, 1024, attn, 1023l * 1024, 1024, 1024, 1023, nullptr, pmx, psum, 4, 4);
    // merge partials + normalize + transpose-write softT [t][m] (row 1023 of soft -> 0)
    softmax_norm_T<<<dim3(16, 16, 32), 256, 0, stream>>>(attn, pmx, psum, softT);
    // A1^T[t][e] = S1^T = sum_m softT[t][m] * E[e][m]
    gemm8<EPI_NONE, bf16><<<dim3(512), 512, 0, stream>>>(
        softT, MB, 1024, En, MB, 1024, A1T, MB, 1024, 1024, BIG, nullptr, nullptr, nullptr, 4, 4);
    // out[o][t] = sum_e Wc[o][e] * A1T[t][e] + b_un[o], f32 -> d_out  (PV gemm folded away)
    gemm8<EPI_BIAS, float><<<dim3(256), 512, 0, stream>>>(
        Wc, 0, 1024, A1T, MB, 1024, out, 512l * 1024, 1024, 1024, BIG, b_un, nullptr, nullptr, 2, 4);
}